// Round 6
// baseline (322.121 us; speedup 1.0000x reference)
//
#include <hip/hip_runtime.h>
#include <hip/hip_bf16.h>
#include <math.h>

// GraphSAGE 3-layer, mean aggr, bf16 activations + MFMA linears. Round 6:
//  - prep: fused bcount + weight-conv + x-conv (independent work, one launch)
//  - bin at 512 blocks (was 128; occupancy was 4.4%, latency-bound)
//  - sage12: fused gather-mean + [A|X]@[Wl|Wr]^T MFMA per 128-row block,
//    ping-pong H1->H2 (fusing removes the AGG global round-trip)
//  - bsort / linmfma3 / agg40lsm unchanged (proven).

#define BK_SHIFT 7
#define BK_NODES 128
#define NB_MAX   1024

typedef __attribute__((ext_vector_type(8))) short short8;
typedef __attribute__((ext_vector_type(4))) float f32x4;

__device__ inline float blo(unsigned v) { union { unsigned u; float f; } c; c.u = v << 16; return c.f; }
__device__ inline float bhi(unsigned v) { union { unsigned u; float f; } c; c.u = v & 0xFFFF0000u; return c.f; }
__device__ inline unsigned short f2bf(float f) {
    union { float f; unsigned u; } c; c.f = f;
    unsigned r = (c.u + 0x7FFFu + ((c.u >> 16) & 1u)) >> 16;
    return (unsigned short)r;
}

// ---------------- prep: bcount (blocks 0..255) + wconv (256..343) + xconv (344..1367) ----------------
__global__ __launch_bounds__(256) void prep_kernel(const int* __restrict__ dstA, int* __restrict__ bcount,
                                                   int E, int NB,
                                                   const float* __restrict__ x, unsigned short* __restrict__ Xb, int n8,
                                                   const float* __restrict__ Wl1, const float* __restrict__ Wr1,
                                                   const float* __restrict__ Wl2, const float* __restrict__ Wr2,
                                                   const float* __restrict__ Wl3, const float* __restrict__ Wr3,
                                                   unsigned short* __restrict__ Wb1,
                                                   unsigned short* __restrict__ Wb2,
                                                   unsigned short* __restrict__ Wb3) {
    int b = blockIdx.x, t = threadIdx.x;
    if (b < 256) {
        __shared__ int lc[NB_MAX];
        for (int i = t; i < NB; i += 256) lc[i] = 0;
        __syncthreads();
        for (int e = b * 256 + t; e < E; e += 256 * 256)
            atomicAdd(&lc[dstA[e] >> BK_SHIFT], 1);
        __syncthreads();
        for (int i = t; i < NB; i += 256)
            if (lc[i]) atomicAdd(&bcount[i], lc[i]);
    } else if (b < 344) {
        int i = (b - 256) * 256 + t;     // 88*256 = 22528 tasks
        if (i < 8192) {
            int c = i >> 7, k = i & 127;
            float v = (k < 64) ? Wl1[c * 64 + k] : Wr1[c * 64 + k - 64];
            Wb1[i] = f2bf(v);
        } else if (i < 16384) {
            int j = i - 8192;
            int c = j >> 7, k = j & 127;
            float v = (k < 64) ? Wl2[c * 64 + k] : Wr2[c * 64 + k - 64];
            Wb2[j] = f2bf(v);
        } else if (i < 22528) {
            int j = i - 16384;
            int c = j >> 6, k = j & 63;
            float v = 0.f;
            if (c < 40) v = Wl3[c * 64 + k];
            else if (c >= 48 && c < 88) v = Wr3[(c - 48) * 64 + k];
            Wb3[j] = f2bf(v);
        }
    } else {
        for (int i = (b - 344) * 256 + t; i < n8; i += 1024 * 256) {
            const float* p = x + (size_t)i * 8;
            float4 a = *(const float4*)p;
            float4 bq = *(const float4*)(p + 4);
            uint4 o;
            o.x = f2bf(a.x) | ((unsigned)f2bf(a.y) << 16);
            o.y = f2bf(a.z) | ((unsigned)f2bf(a.w) << 16);
            o.z = f2bf(bq.x) | ((unsigned)f2bf(bq.y) << 16);
            o.w = f2bf(bq.z) | ((unsigned)f2bf(bq.w) << 16);
            *(uint4*)(Xb + (size_t)i * 8) = o;
        }
    }
}

// ---------------- scan bucket counts ----------------
__global__ __launch_bounds__(1024) void bscan_kernel(const int* __restrict__ bcount,
                                                     int* __restrict__ bbase,
                                                     int* __restrict__ cursor, int NB, int E) {
    __shared__ int s[1024];
    int t = threadIdx.x;
    int v = (t < NB) ? bcount[t] : 0;
    s[t] = v;
    __syncthreads();
    for (int off = 1; off < 1024; off <<= 1) {
        int x = 0;
        if (t >= off) x = s[t - off];
        __syncthreads();
        s[t] += x;
        __syncthreads();
    }
    if (t < NB) {
        int ex = s[t] - v;
        bbase[t] = ex;
        cursor[t] = ex;
    }
    if (t == 0) bbase[NB] = E;
}

// ---------------- bin edges (src | dstLocal<<24) ----------------
__global__ __launch_bounds__(256) void bin_kernel(const int* __restrict__ srcA,
                                                  const int* __restrict__ dstA,
                                                  int* __restrict__ cursor,
                                                  int* __restrict__ binned, int E, int NB) {
    __shared__ int lc[NB_MAX];
    __shared__ int lbase[NB_MAX];
    int t = threadIdx.x;
    int chunk = (E + gridDim.x - 1) / gridDim.x;
    int e0 = blockIdx.x * chunk;
    int e1 = min(E, e0 + chunk);
    for (int i = t; i < NB; i += 256) lc[i] = 0;
    __syncthreads();
    for (int e = e0 + t; e < e1; e += 256)
        atomicAdd(&lc[dstA[e] >> BK_SHIFT], 1);
    __syncthreads();
    for (int i = t; i < NB; i += 256) {
        int c = lc[i];
        lbase[i] = c ? atomicAdd(&cursor[i], c) : 0;
    }
    __syncthreads();
    for (int i = t; i < NB; i += 256) lc[i] = 0;
    __syncthreads();
    for (int e = e0 + t; e < e1; e += 256) {
        int d = dstA[e];
        int b = d >> BK_SHIFT;
        int r = atomicAdd(&lc[b], 1);
        binned[lbase[b] + r] = srcA[e] | ((d & (BK_NODES - 1)) << 24);
    }
}

// ---------------- per-bucket counting sort -> sorted CSR ----------------
__global__ __launch_bounds__(256) void bsort_kernel(const int* __restrict__ binned,
                                                    const int* __restrict__ bbase,
                                                    int* __restrict__ col,
                                                    int* __restrict__ row_start, int N) {
    __shared__ int cnt[BK_NODES];
    __shared__ int base[BK_NODES];
    __shared__ int s[BK_NODES];
    int b = blockIdx.x, t = threadIdx.x;
    int e0 = bbase[b], e1 = bbase[b + 1];
    if (t < BK_NODES) cnt[t] = 0;
    __syncthreads();
    for (int e = e0 + t; e < e1; e += 256)
        atomicAdd(&cnt[(unsigned)binned[e] >> 24], 1);
    __syncthreads();
    int v = (t < BK_NODES) ? cnt[t] : 0;
    if (t < BK_NODES) s[t] = v;
    __syncthreads();
    for (int off = 1; off < BK_NODES; off <<= 1) {
        int x = 0;
        if (t < BK_NODES && t >= off) x = s[t - off];
        __syncthreads();
        if (t < BK_NODES) s[t] += x;
        __syncthreads();
    }
    if (t < BK_NODES) {
        base[t] = e0 + s[t] - v;
        int node = b * BK_NODES + t;
        if (node < N) row_start[node] = base[t];
        cnt[t] = 0;
    }
    if (b == gridDim.x - 1 && t == 0) row_start[N] = e1;
    __syncthreads();
    for (int e = e0 + t; e < e1; e += 256) {
        unsigned p = (unsigned)binned[e];
        int dl = p >> 24;
        int pos = base[dl] + atomicAdd(&cnt[dl], 1);
        col[pos] = p & 0xFFFFFF;
    }
}

// ---------------- fused SAGE layer 1/2: gather-mean into LDS + MFMA ----------------
// 128 rows/block, 512 threads (8 waves). Ys[row] = [agg(0..63) | self(64..127)].
// OUT = relu([agg|self] @ Wb^T + b). NOT in-place safe (random gathers) -> ping-pong.
__global__ __launch_bounds__(512) void sage12_kernel(const unsigned short* __restrict__ X,
                                                     const unsigned short* __restrict__ Wb,
                                                     const float* __restrict__ bias,
                                                     const int* __restrict__ rs,
                                                     const int* __restrict__ col,
                                                     unsigned short* __restrict__ OUT,
                                                     int N) {
    __shared__ unsigned short Ys[128][136];
    __shared__ unsigned short Ws[64][136];
    int t = threadIdx.x;
    int rowbase = blockIdx.x * 128;
    // stage weights: 64 rows x 16 chunks of 8 = 1024 chunks, 2 iters
#pragma unroll
    for (int it = 0; it < 2; ++it) {
        int idx = it * 512 + t;
        int row = idx >> 4, c = idx & 15;
        *(short8*)&Ws[row][c * 8] = *(const short8*)(Wb + (size_t)row * 128 + c * 8);
    }
    // stage self rows into cols 64..127: 128 rows x 8 chunks = 1024, 2 iters
#pragma unroll
    for (int it = 0; it < 2; ++it) {
        int idx = it * 512 + t;
        int row = idx >> 3, c = idx & 7;
        int grow = rowbase + row;
        if (grow >= N) grow = N - 1;
        *(short8*)&Ys[row][64 + c * 8] = *(const short8*)(X + (size_t)grow * 64 + c * 8);
    }
    // gather-mean into cols 0..63: 32 groups of 16 lanes, 4 nodes each
    {
        int g = t >> 4, lane = t & 15;
        const unsigned short* lp = X + lane * 4;
#pragma unroll
        for (int k = 0; k < 4; ++k) {
            int row = g + k * 32;
            int node = rowbase + row;
            float ax = 0.f, ay = 0.f, az = 0.f, aw = 0.f;
            if (node < N) {
                int s = rs[node], d = rs[node + 1] - s;
                int j = 0;
                for (; j + 3 < d; j += 4) {
                    int c0 = col[s + j], c1 = col[s + j + 1];
                    int c2 = col[s + j + 2], c3 = col[s + j + 3];
                    uint2 q0 = *(const uint2*)(lp + (size_t)c0 * 64);
                    uint2 q1 = *(const uint2*)(lp + (size_t)c1 * 64);
                    uint2 q2 = *(const uint2*)(lp + (size_t)c2 * 64);
                    uint2 q3 = *(const uint2*)(lp + (size_t)c3 * 64);
                    ax += (blo(q0.x) + blo(q1.x)) + (blo(q2.x) + blo(q3.x));
                    ay += (bhi(q0.x) + bhi(q1.x)) + (bhi(q2.x) + bhi(q3.x));
                    az += (blo(q0.y) + blo(q1.y)) + (blo(q2.y) + blo(q3.y));
                    aw += (bhi(q0.y) + bhi(q1.y)) + (bhi(q2.y) + bhi(q3.y));
                }
                for (; j < d; ++j) {
                    int c0 = col[s + j];
                    uint2 q0 = *(const uint2*)(lp + (size_t)c0 * 64);
                    ax += blo(q0.x); ay += bhi(q0.x); az += blo(q0.y); aw += bhi(q0.y);
                }
                float w = 1.f / (float)(d > 0 ? d : 1);
                ax *= w; ay *= w; az *= w; aw *= w;
            }
            uint2 o;
            o.x = f2bf(ax) | ((unsigned)f2bf(ay) << 16);
            o.y = f2bf(az) | ((unsigned)f2bf(aw) << 16);
            *(uint2*)&Ys[row][lane * 4] = o;
        }
    }
    __syncthreads();
    // MFMA: wave w handles A-rows [16w,16w+16), all 64 output cols
    int l = t & 63, w = t >> 6;
    int lrow = l & 15, lk = l >> 4;
    f32x4 acc0 = {0.f, 0.f, 0.f, 0.f};
    f32x4 acc1 = acc0, acc2 = acc0, acc3 = acc0;
#pragma unroll
    for (int kk = 0; kk < 4; ++kk) {
        int ko = kk * 32 + lk * 8;
        short8 a  = *(const short8*)&Ys[16 * w + lrow][ko];
        short8 b0 = *(const short8*)&Ws[lrow][ko];
        short8 b1 = *(const short8*)&Ws[16 + lrow][ko];
        short8 b2 = *(const short8*)&Ws[32 + lrow][ko];
        short8 b3 = *(const short8*)&Ws[48 + lrow][ko];
        acc0 = __builtin_amdgcn_mfma_f32_16x16x32_bf16(a, b0, acc0, 0, 0, 0);
        acc1 = __builtin_amdgcn_mfma_f32_16x16x32_bf16(a, b1, acc1, 0, 0, 0);
        acc2 = __builtin_amdgcn_mfma_f32_16x16x32_bf16(a, b2, acc2, 0, 0, 0);
        acc3 = __builtin_amdgcn_mfma_f32_16x16x32_bf16(a, b3, acc3, 0, 0, 0);
    }
#define EPI12(nt, accv)                                                   \
    {                                                                     \
        int colc = 16 * (nt) + lrow;                                      \
        float bv = bias[colc];                                            \
        _Pragma("unroll") for (int i = 0; i < 4; ++i) {                   \
            int grow = rowbase + 16 * w + lk * 4 + i;                     \
            if (grow < N) {                                               \
                float v = fmaxf(accv[i] + bv, 0.f);                       \
                OUT[(size_t)grow * 64 + colc] = f2bf(v);                  \
            }                                                             \
        }                                                                 \
    }
    EPI12(0, acc0) EPI12(1, acc1) EPI12(2, acc2) EPI12(3, acc3)
#undef EPI12
}

// ---------------- MFMA linear 3: Z = h2@Wl3^T (bf16), R = h2@Wr3^T + b3 (fp32) ----------------
__global__ __launch_bounds__(256) void linmfma3_kernel(const unsigned short* __restrict__ H,
                                                       const unsigned short* __restrict__ Wb3,
                                                       const float* __restrict__ b3,
                                                       unsigned short* __restrict__ Z,
                                                       float* __restrict__ R,
                                                       int N) {
    __shared__ unsigned short Ys[64][72];
    __shared__ unsigned short Ws[96][72];
    int t = threadIdx.x;
    int rowbase = blockIdx.x * 64;
#pragma unroll
    for (int it = 0; it < 2; ++it) {
        int idx = it * 256 + t;
        int row = idx >> 3, c = idx & 7;
        int grow = rowbase + row;
        if (grow >= N) grow = N - 1;
        *(short8*)&Ys[row][c * 8] = *(const short8*)(H + (size_t)grow * 64 + c * 8);
    }
#pragma unroll
    for (int it = 0; it < 3; ++it) {
        int idx = it * 256 + t;
        int row = idx >> 3, c = idx & 7;
        *(short8*)&Ws[row][c * 8] = *(const short8*)(Wb3 + (size_t)row * 64 + c * 8);
    }
    __syncthreads();
    int l = t & 63, w = t >> 6;
    int lrow = l & 15, lk = l >> 4;
    f32x4 acc0 = {0.f, 0.f, 0.f, 0.f};
    f32x4 acc1 = acc0, acc2 = acc0, acc3 = acc0, acc4 = acc0, acc5 = acc0;
#pragma unroll
    for (int kk = 0; kk < 2; ++kk) {
        int ko = kk * 32 + lk * 8;
        short8 a  = *(const short8*)&Ys[16 * w + lrow][ko];
        short8 b0 = *(const short8*)&Ws[lrow][ko];
        short8 b1 = *(const short8*)&Ws[16 + lrow][ko];
        short8 b2 = *(const short8*)&Ws[32 + lrow][ko];
        short8 b3f = *(const short8*)&Ws[48 + lrow][ko];
        short8 b4 = *(const short8*)&Ws[64 + lrow][ko];
        short8 b5 = *(const short8*)&Ws[80 + lrow][ko];
        acc0 = __builtin_amdgcn_mfma_f32_16x16x32_bf16(a, b0, acc0, 0, 0, 0);
        acc1 = __builtin_amdgcn_mfma_f32_16x16x32_bf16(a, b1, acc1, 0, 0, 0);
        acc2 = __builtin_amdgcn_mfma_f32_16x16x32_bf16(a, b2, acc2, 0, 0, 0);
        acc3 = __builtin_amdgcn_mfma_f32_16x16x32_bf16(a, b3f, acc3, 0, 0, 0);
        acc4 = __builtin_amdgcn_mfma_f32_16x16x32_bf16(a, b4, acc4, 0, 0, 0);
        acc5 = __builtin_amdgcn_mfma_f32_16x16x32_bf16(a, b5, acc5, 0, 0, 0);
    }
#define EPI3(nt, accv)                                                     \
    {                                                                      \
        int colc = 16 * (nt) + lrow;                                       \
        _Pragma("unroll") for (int i = 0; i < 4; ++i) {                    \
            int grow = rowbase + 16 * w + lk * 4 + i;                      \
            if (grow < N) {                                                \
                float v = accv[i];                                         \
                if (colc < 40) {                                           \
                    Z[(size_t)grow * 40 + colc] = f2bf(v);                 \
                } else if (colc >= 48 && colc < 88) {                      \
                    R[(size_t)grow * 40 + (colc - 48)] = v + b3[colc - 48];\
                }                                                          \
            }                                                              \
        }                                                                  \
    }
    EPI3(0, acc0) EPI3(1, acc1) EPI3(2, acc2) EPI3(3, acc3) EPI3(4, acc4) EPI3(5, acc5)
#undef EPI3
}

// ---------------- agg(40 bf16) + self-path add + fused log_softmax ----------------
__global__ __launch_bounds__(256) void agg40lsm_kernel(const unsigned short* __restrict__ Z,
                                                       const int* __restrict__ rs,
                                                       const int* __restrict__ col,
                                                       float* __restrict__ out, int n) {
    int t = threadIdx.x;
    int node = blockIdx.x * 16 + (t >> 4);
    if (node >= n) return;
    int lane = t & 15;
    bool act = lane < 10;
    int s = rs[node], d = rs[node + 1] - s;
    const unsigned short* lp = Z + lane * 4;
    float ax = 0.f, ay = 0.f, az = 0.f, aw = 0.f;
    int j = 0;
    for (; j + 3 < d; j += 4) {
        int c0 = col[s + j], c1 = col[s + j + 1];
        int c2 = col[s + j + 2], c3 = col[s + j + 3];
        if (act) {
            uint2 q0 = *(const uint2*)(lp + (size_t)c0 * 40);
            uint2 q1 = *(const uint2*)(lp + (size_t)c1 * 40);
            uint2 q2 = *(const uint2*)(lp + (size_t)c2 * 40);
            uint2 q3 = *(const uint2*)(lp + (size_t)c3 * 40);
            ax += (blo(q0.x) + blo(q1.x)) + (blo(q2.x) + blo(q3.x));
            ay += (bhi(q0.x) + bhi(q1.x)) + (bhi(q2.x) + bhi(q3.x));
            az += (blo(q0.y) + blo(q1.y)) + (blo(q2.y) + blo(q3.y));
            aw += (bhi(q0.y) + bhi(q1.y)) + (bhi(q2.y) + bhi(q3.y));
        }
    }
    for (; j < d; ++j) {
        int c0 = col[s + j];
        if (act) {
            uint2 q0 = *(const uint2*)(lp + (size_t)c0 * 40);
            ax += blo(q0.x); ay += bhi(q0.x); az += blo(q0.y); aw += bhi(q0.y);
        }
    }
    float w = 1.f / (float)(d > 0 ? d : 1);
    if (act) {
        float4 rv = *(const float4*)(out + (size_t)node * 40 + lane * 4);
        ax = ax * w + rv.x; ay = ay * w + rv.y;
        az = az * w + rv.z; aw = aw * w + rv.w;
    }
    float mx = act ? fmaxf(fmaxf(ax, ay), fmaxf(az, aw)) : -3.4e38f;
#pragma unroll
    for (int off = 1; off < 16; off <<= 1) mx = fmaxf(mx, __shfl_xor(mx, off, 16));
    float ssum = act ? (expf(ax - mx) + expf(ay - mx) + expf(az - mx) + expf(aw - mx)) : 0.f;
#pragma unroll
    for (int off = 1; off < 16; off <<= 1) ssum += __shfl_xor(ssum, off, 16);
    float lg = mx + logf(ssum);
    if (act) {
        float4 o;
        o.x = ax - lg; o.y = ay - lg; o.z = az - lg; o.w = aw - lg;
        *(float4*)(out + (size_t)node * 40 + lane * 4) = o;
    }
}

// ---------------- launch ----------------
extern "C" void kernel_launch(void* const* d_in, const int* in_sizes, int n_in,
                              void* d_out, int out_size, void* d_ws, size_t ws_size,
                              hipStream_t stream) {
    const float* x   = (const float*)d_in[0];
    const int*   ei  = (const int*)d_in[1];
    const float* Wl1 = (const float*)d_in[2];
    const float* Wr1 = (const float*)d_in[3];
    const float* b1  = (const float*)d_in[4];
    const float* Wl2 = (const float*)d_in[5];
    const float* Wr2 = (const float*)d_in[6];
    const float* b2  = (const float*)d_in[7];
    const float* Wl3 = (const float*)d_in[8];
    const float* Wr3 = (const float*)d_in[9];
    const float* b3  = (const float*)d_in[10];
    float* out = (float*)d_out;

    const int N = in_sizes[0] / 64;
    const int E = in_sizes[1] / 2;
    const int NB = (N + BK_NODES - 1) / BK_NODES;
    const int* srcA = ei;
    const int* dstA = ei + E;

    char* ws = (char*)d_ws;
    size_t off = 0;
    auto alloc = [&](size_t bytes) {
        off = (off + 255) & ~(size_t)255;
        char* p = ws + off;
        off += bytes;
        return p;
    };
    int* bcount    = (int*)alloc((size_t)(NB_MAX + 1) * 4);
    int* bbase     = (int*)alloc((size_t)(NB_MAX + 1) * 4);
    int* cursor    = (int*)alloc((size_t)NB_MAX * 4);
    int* binned    = (int*)alloc((size_t)E * 4);
    int* col       = (int*)alloc((size_t)E * 4);
    int* row_start = (int*)alloc((size_t)(N + 1) * 4);
    unsigned short* Xb  = (unsigned short*)alloc((size_t)N * 64 * 2);
    unsigned short* H1  = (unsigned short*)alloc((size_t)N * 64 * 2);
    unsigned short* H2  = (unsigned short*)alloc((size_t)N * 64 * 2);
    unsigned short* Zb  = (unsigned short*)alloc((size_t)N * 40 * 2);
    unsigned short* Wb1 = (unsigned short*)alloc(8192 * 2);
    unsigned short* Wb2 = (unsigned short*)alloc(8192 * 2);
    unsigned short* Wb3 = (unsigned short*)alloc(6144 * 2);

    // prep: bucket count + weight conv + x conv (fused, independent tasks)
    hipMemsetAsync(bcount, 0, (size_t)(NB + 1) * 4, stream);
    prep_kernel<<<1368, 256, 0, stream>>>(dstA, bcount, E, NB, x, Xb, N * 64 / 8,
                                          Wl1, Wr1, Wl2, Wr2, Wl3, Wr3, Wb1, Wb2, Wb3);
    bscan_kernel<<<1, 1024, 0, stream>>>(bcount, bbase, cursor, NB, E);
    bin_kernel<<<512, 256, 0, stream>>>(srcA, dstA, cursor, binned, E, NB);
    bsort_kernel<<<NB, 256, 0, stream>>>(binned, bbase, col, row_start, N);

    int grid128 = (N + 127) / 128;
    // layer 1: Xb -> H1, layer 2: H1 -> H2 (ping-pong; fused gather is not in-place safe)
    sage12_kernel<<<grid128, 512, 0, stream>>>(Xb, Wb1, b1, row_start, col, H1, N);
    sage12_kernel<<<grid128, 512, 0, stream>>>(H1, Wb2, b2, row_start, col, H2, N);

    // layer 3: pre-transform (agg is linear), then agg(40) + self + log_softmax
    linmfma3_kernel<<<(N + 63) / 64, 256, 0, stream>>>(H2, Wb3, b3, Zb, out, N);
    agg40lsm_kernel<<<(N + 15) / 16, 256, 0, stream>>>(Zb, row_start, col, out, N);
}

// Round 9
// 284.950 us; speedup vs baseline: 1.1304x; 1.1304x over previous
//
#include <hip/hip_runtime.h>
#include <hip/hip_bf16.h>
#include <math.h>

// GraphSAGE 3-layer, mean aggr, bf16 + MFMA. Round 7 (2nd resubmit after two
// broker timeouts): UN-fuse sage12 (fusion lost occupancy during gather; r6
// 62us vs r5 ~47us split). Keep prep fusion + bin@512. Gather kernels rebuilt
// for MLP: 8-lane groups x uint4 (16B/lane).
//   prep(bcount+wconv+xconv) -> bscan -> bin -> bsort => sorted CSR
//   L1/L2: agg64(8-lane) -> linmfma12 (K=128 [A|X]@[Wl|Wr]^T, relu)
//   L3: linmfma3 (Z bf16, R fp32->out) -> agg40lsm (8-lane, fused log_softmax)

#define BK_SHIFT 7
#define BK_NODES 128
#define NB_MAX   1024

typedef __attribute__((ext_vector_type(8))) short short8;
typedef __attribute__((ext_vector_type(4))) float f32x4;

__device__ inline float blo(unsigned v) { union { unsigned u; float f; } c; c.u = v << 16; return c.f; }
__device__ inline float bhi(unsigned v) { union { unsigned u; float f; } c; c.u = v & 0xFFFF0000u; return c.f; }
__device__ inline unsigned short f2bf(float f) {
    union { float f; unsigned u; } c; c.f = f;
    unsigned r = (c.u + 0x7FFFu + ((c.u >> 16) & 1u)) >> 16;
    return (unsigned short)r;
}

// ---------------- prep: bcount (blocks 0..255) + wconv (256..343) + xconv (344..1367) ----------------
__global__ __launch_bounds__(256) void prep_kernel(const int* __restrict__ dstA, int* __restrict__ bcount,
                                                   int E, int NB,
                                                   const float* __restrict__ x, unsigned short* __restrict__ Xb, int n8,
                                                   const float* __restrict__ Wl1, const float* __restrict__ Wr1,
                                                   const float* __restrict__ Wl2, const float* __restrict__ Wr2,
                                                   const float* __restrict__ Wl3, const float* __restrict__ Wr3,
                                                   unsigned short* __restrict__ Wb1,
                                                   unsigned short* __restrict__ Wb2,
                                                   unsigned short* __restrict__ Wb3) {
    int b = blockIdx.x, t = threadIdx.x;
    if (b < 256) {
        __shared__ int lc[NB_MAX];
        for (int i = t; i < NB; i += 256) lc[i] = 0;
        __syncthreads();
        for (int e = b * 256 + t; e < E; e += 256 * 256)
            atomicAdd(&lc[dstA[e] >> BK_SHIFT], 1);
        __syncthreads();
        for (int i = t; i < NB; i += 256)
            if (lc[i]) atomicAdd(&bcount[i], lc[i]);
    } else if (b < 344) {
        int i = (b - 256) * 256 + t;
        if (i < 8192) {
            int c = i >> 7, k = i & 127;
            float v = (k < 64) ? Wl1[c * 64 + k] : Wr1[c * 64 + k - 64];
            Wb1[i] = f2bf(v);
        } else if (i < 16384) {
            int j = i - 8192;
            int c = j >> 7, k = j & 127;
            float v = (k < 64) ? Wl2[c * 64 + k] : Wr2[c * 64 + k - 64];
            Wb2[j] = f2bf(v);
        } else if (i < 22528) {
            int j = i - 16384;
            int c = j >> 6, k = j & 63;
            float v = 0.f;
            if (c < 40) v = Wl3[c * 64 + k];
            else if (c >= 48 && c < 88) v = Wr3[(c - 48) * 64 + k];
            Wb3[j] = f2bf(v);
        }
    } else {
        for (int i = (b - 344) * 256 + t; i < n8; i += 1024 * 256) {
            const float* p = x + (size_t)i * 8;
            float4 a = *(const float4*)p;
            float4 bq = *(const float4*)(p + 4);
            uint4 o;
            o.x = f2bf(a.x) | ((unsigned)f2bf(a.y) << 16);
            o.y = f2bf(a.z) | ((unsigned)f2bf(a.w) << 16);
            o.z = f2bf(bq.x) | ((unsigned)f2bf(bq.y) << 16);
            o.w = f2bf(bq.z) | ((unsigned)f2bf(bq.w) << 16);
            *(uint4*)(Xb + (size_t)i * 8) = o;
        }
    }
}

// ---------------- scan bucket counts ----------------
__global__ __launch_bounds__(1024) void bscan_kernel(const int* __restrict__ bcount,
                                                     int* __restrict__ bbase,
                                                     int* __restrict__ cursor, int NB, int E) {
    __shared__ int s[1024];
    int t = threadIdx.x;
    int v = (t < NB) ? bcount[t] : 0;
    s[t] = v;
    __syncthreads();
    for (int off = 1; off < 1024; off <<= 1) {
        int x = 0;
        if (t >= off) x = s[t - off];
        __syncthreads();
        s[t] += x;
        __syncthreads();
    }
    if (t < NB) {
        int ex = s[t] - v;
        bbase[t] = ex;
        cursor[t] = ex;
    }
    if (t == 0) bbase[NB] = E;
}

// ---------------- bin edges (src | dstLocal<<24) ----------------
__global__ __launch_bounds__(256) void bin_kernel(const int* __restrict__ srcA,
                                                  const int* __restrict__ dstA,
                                                  int* __restrict__ cursor,
                                                  int* __restrict__ binned, int E, int NB) {
    __shared__ int lc[NB_MAX];
    __shared__ int lbase[NB_MAX];
    int t = threadIdx.x;
    int chunk = (E + gridDim.x - 1) / gridDim.x;
    int e0 = blockIdx.x * chunk;
    int e1 = min(E, e0 + chunk);
    for (int i = t; i < NB; i += 256) lc[i] = 0;
    __syncthreads();
    for (int e = e0 + t; e < e1; e += 256)
        atomicAdd(&lc[dstA[e] >> BK_SHIFT], 1);
    __syncthreads();
    for (int i = t; i < NB; i += 256) {
        int c = lc[i];
        lbase[i] = c ? atomicAdd(&cursor[i], c) : 0;
    }
    __syncthreads();
    for (int i = t; i < NB; i += 256) lc[i] = 0;
    __syncthreads();
    for (int e = e0 + t; e < e1; e += 256) {
        int d = dstA[e];
        int b = d >> BK_SHIFT;
        int r = atomicAdd(&lc[b], 1);
        binned[lbase[b] + r] = srcA[e] | ((d & (BK_NODES - 1)) << 24);
    }
}

// ---------------- per-bucket counting sort -> sorted CSR ----------------
__global__ __launch_bounds__(256) void bsort_kernel(const int* __restrict__ binned,
                                                    const int* __restrict__ bbase,
                                                    int* __restrict__ col,
                                                    int* __restrict__ row_start, int N) {
    __shared__ int cnt[BK_NODES];
    __shared__ int base[BK_NODES];
    __shared__ int s[BK_NODES];
    int b = blockIdx.x, t = threadIdx.x;
    int e0 = bbase[b], e1 = bbase[b + 1];
    if (t < BK_NODES) cnt[t] = 0;
    __syncthreads();
    for (int e = e0 + t; e < e1; e += 256)
        atomicAdd(&cnt[(unsigned)binned[e] >> 24], 1);
    __syncthreads();
    int v = (t < BK_NODES) ? cnt[t] : 0;
    if (t < BK_NODES) s[t] = v;
    __syncthreads();
    for (int off = 1; off < BK_NODES; off <<= 1) {
        int x = 0;
        if (t < BK_NODES && t >= off) x = s[t - off];
        __syncthreads();
        if (t < BK_NODES) s[t] += x;
        __syncthreads();
    }
    if (t < BK_NODES) {
        base[t] = e0 + s[t] - v;
        int node = b * BK_NODES + t;
        if (node < N) row_start[node] = base[t];
        cnt[t] = 0;
    }
    if (b == gridDim.x - 1 && t == 0) row_start[N] = e1;
    __syncthreads();
    for (int e = e0 + t; e < e1; e += 256) {
        unsigned p = (unsigned)binned[e];
        int dl = p >> 24;
        int pos = base[dl] + atomicAdd(&cnt[dl], 1);
        col[pos] = p & 0xFFFFFF;
    }
}

// ---------------- mean aggregation, 64 bf16 dims: 8-lane group/node, uint4 ----------------
__global__ __launch_bounds__(256) void agg64_kernel(const unsigned short* __restrict__ X,
                                                    const int* __restrict__ rs,
                                                    const int* __restrict__ col,
                                                    unsigned short* __restrict__ OUT, int n) {
    int t = threadIdx.x;
    int node = blockIdx.x * 32 + (t >> 3);
    if (node >= n) return;
    int lane = t & 7;
    int s = rs[node], d = rs[node + 1] - s;
    const unsigned short* lp = X + lane * 8;
    float a0 = 0.f, a1 = 0.f, a2 = 0.f, a3 = 0.f, a4 = 0.f, a5 = 0.f, a6 = 0.f, a7 = 0.f;
    int j = 0;
    for (; j + 3 < d; j += 4) {
        int c0 = col[s + j], c1 = col[s + j + 1];
        int c2 = col[s + j + 2], c3 = col[s + j + 3];
        uint4 q0 = *(const uint4*)(lp + (size_t)c0 * 64);
        uint4 q1 = *(const uint4*)(lp + (size_t)c1 * 64);
        uint4 q2 = *(const uint4*)(lp + (size_t)c2 * 64);
        uint4 q3 = *(const uint4*)(lp + (size_t)c3 * 64);
        a0 += (blo(q0.x) + blo(q1.x)) + (blo(q2.x) + blo(q3.x));
        a1 += (bhi(q0.x) + bhi(q1.x)) + (bhi(q2.x) + bhi(q3.x));
        a2 += (blo(q0.y) + blo(q1.y)) + (blo(q2.y) + blo(q3.y));
        a3 += (bhi(q0.y) + bhi(q1.y)) + (bhi(q2.y) + bhi(q3.y));
        a4 += (blo(q0.z) + blo(q1.z)) + (blo(q2.z) + blo(q3.z));
        a5 += (bhi(q0.z) + bhi(q1.z)) + (bhi(q2.z) + bhi(q3.z));
        a6 += (blo(q0.w) + blo(q1.w)) + (blo(q2.w) + blo(q3.w));
        a7 += (bhi(q0.w) + bhi(q1.w)) + (bhi(q2.w) + bhi(q3.w));
    }
    for (; j < d; ++j) {
        int c0 = col[s + j];
        uint4 q0 = *(const uint4*)(lp + (size_t)c0 * 64);
        a0 += blo(q0.x); a1 += bhi(q0.x); a2 += blo(q0.y); a3 += bhi(q0.y);
        a4 += blo(q0.z); a5 += bhi(q0.z); a6 += blo(q0.w); a7 += bhi(q0.w);
    }
    float w = 1.f / (float)(d > 0 ? d : 1);
    a0 *= w; a1 *= w; a2 *= w; a3 *= w; a4 *= w; a5 *= w; a6 *= w; a7 *= w;
    uint4 o;
    o.x = f2bf(a0) | ((unsigned)f2bf(a1) << 16);
    o.y = f2bf(a2) | ((unsigned)f2bf(a3) << 16);
    o.z = f2bf(a4) | ((unsigned)f2bf(a5) << 16);
    o.w = f2bf(a6) | ((unsigned)f2bf(a7) << 16);
    *(uint4*)(OUT + (size_t)node * 64 + lane * 8) = o;
}

// ---------------- MFMA linear 1/2: OUT = relu([A|X]@Wb^T + b), K=128 ----------------
__global__ __launch_bounds__(256) void linmfma12_kernel(const unsigned short* __restrict__ A,
                                                        const unsigned short* __restrict__ X,
                                                        const unsigned short* __restrict__ Wb,
                                                        const float* __restrict__ bias,
                                                        unsigned short* __restrict__ OUT,
                                                        int N) {
    __shared__ unsigned short Ys[64][136];
    __shared__ unsigned short Ws[64][136];
    int t = threadIdx.x;
    int rowbase = blockIdx.x * 64;
#pragma unroll
    for (int it = 0; it < 4; ++it) {
        int idx = it * 256 + t;
        int row = idx >> 4, c = idx & 15;
        int grow = rowbase + row;
        if (grow >= N) grow = N - 1;
        const unsigned short* src = (c < 8) ? (A + (size_t)grow * 64 + c * 8)
                                            : (X + (size_t)grow * 64 + (c - 8) * 8);
        *(short8*)&Ys[row][c * 8] = *(const short8*)src;
        *(short8*)&Ws[row][c * 8] = *(const short8*)(Wb + (size_t)row * 128 + c * 8);
    }
    __syncthreads();
    int l = t & 63, w = t >> 6;
    int lrow = l & 15, lk = l >> 4;
    f32x4 acc0 = {0.f, 0.f, 0.f, 0.f};
    f32x4 acc1 = acc0, acc2 = acc0, acc3 = acc0;
#pragma unroll
    for (int kk = 0; kk < 4; ++kk) {
        int ko = kk * 32 + lk * 8;
        short8 a  = *(const short8*)&Ys[16 * w + lrow][ko];
        short8 b0 = *(const short8*)&Ws[lrow][ko];
        short8 b1 = *(const short8*)&Ws[16 + lrow][ko];
        short8 b2 = *(const short8*)&Ws[32 + lrow][ko];
        short8 b3 = *(const short8*)&Ws[48 + lrow][ko];
        acc0 = __builtin_amdgcn_mfma_f32_16x16x32_bf16(a, b0, acc0, 0, 0, 0);
        acc1 = __builtin_amdgcn_mfma_f32_16x16x32_bf16(a, b1, acc1, 0, 0, 0);
        acc2 = __builtin_amdgcn_mfma_f32_16x16x32_bf16(a, b2, acc2, 0, 0, 0);
        acc3 = __builtin_amdgcn_mfma_f32_16x16x32_bf16(a, b3, acc3, 0, 0, 0);
    }
#define EPI12(nt, accv)                                                   \
    {                                                                     \
        int colc = 16 * (nt) + lrow;                                      \
        float bv = bias[colc];                                            \
        _Pragma("unroll") for (int i = 0; i < 4; ++i) {                   \
            int grow = rowbase + 16 * w + lk * 4 + i;                     \
            if (grow < N) {                                               \
                float v = fmaxf(accv[i] + bv, 0.f);                       \
                OUT[(size_t)grow * 64 + colc] = f2bf(v);                  \
            }                                                             \
        }                                                                 \
    }
    EPI12(0, acc0) EPI12(1, acc1) EPI12(2, acc2) EPI12(3, acc3)
#undef EPI12
}

// ---------------- MFMA linear 3: Z = h2@Wl3^T (bf16), R = h2@Wr3^T + b3 (fp32) ----------------
__global__ __launch_bounds__(256) void linmfma3_kernel(const unsigned short* __restrict__ H,
                                                       const unsigned short* __restrict__ Wb3,
                                                       const float* __restrict__ b3,
                                                       unsigned short* __restrict__ Z,
                                                       float* __restrict__ R,
                                                       int N) {
    __shared__ unsigned short Ys[64][72];
    __shared__ unsigned short Ws[96][72];
    int t = threadIdx.x;
    int rowbase = blockIdx.x * 64;
#pragma unroll
    for (int it = 0; it < 2; ++it) {
        int idx = it * 256 + t;
        int row = idx >> 3, c = idx & 7;
        int grow = rowbase + row;
        if (grow >= N) grow = N - 1;
        *(short8*)&Ys[row][c * 8] = *(const short8*)(H + (size_t)grow * 64 + c * 8);
    }
#pragma unroll
    for (int it = 0; it < 3; ++it) {
        int idx = it * 256 + t;
        int row = idx >> 3, c = idx & 7;
        *(short8*)&Ws[row][c * 8] = *(const short8*)(Wb3 + (size_t)row * 64 + c * 8);
    }
    __syncthreads();
    int l = t & 63, w = t >> 6;
    int lrow = l & 15, lk = l >> 4;
    f32x4 acc0 = {0.f, 0.f, 0.f, 0.f};
    f32x4 acc1 = acc0, acc2 = acc0, acc3 = acc0, acc4 = acc0, acc5 = acc0;
#pragma unroll
    for (int kk = 0; kk < 2; ++kk) {
        int ko = kk * 32 + lk * 8;
        short8 a  = *(const short8*)&Ys[16 * w + lrow][ko];
        short8 b0 = *(const short8*)&Ws[lrow][ko];
        short8 b1 = *(const short8*)&Ws[16 + lrow][ko];
        short8 b2 = *(const short8*)&Ws[32 + lrow][ko];
        short8 b3f = *(const short8*)&Ws[48 + lrow][ko];
        short8 b4 = *(const short8*)&Ws[64 + lrow][ko];
        short8 b5 = *(const short8*)&Ws[80 + lrow][ko];
        acc0 = __builtin_amdgcn_mfma_f32_16x16x32_bf16(a, b0, acc0, 0, 0, 0);
        acc1 = __builtin_amdgcn_mfma_f32_16x16x32_bf16(a, b1, acc1, 0, 0, 0);
        acc2 = __builtin_amdgcn_mfma_f32_16x16x32_bf16(a, b2, acc2, 0, 0, 0);
        acc3 = __builtin_amdgcn_mfma_f32_16x16x32_bf16(a, b3f, acc3, 0, 0, 0);
        acc4 = __builtin_amdgcn_mfma_f32_16x16x32_bf16(a, b4, acc4, 0, 0, 0);
        acc5 = __builtin_amdgcn_mfma_f32_16x16x32_bf16(a, b5, acc5, 0, 0, 0);
    }
#define EPI3(nt, accv)                                                     \
    {                                                                      \
        int colc = 16 * (nt) + lrow;                                       \
        _Pragma("unroll") for (int i = 0; i < 4; ++i) {                    \
            int grow = rowbase + 16 * w + lk * 4 + i;                      \
            if (grow < N) {                                                \
                float v = accv[i];                                         \
                if (colc < 40) {                                           \
                    Z[(size_t)grow * 40 + colc] = f2bf(v);                 \
                } else if (colc >= 48 && colc < 88) {                      \
                    R[(size_t)grow * 40 + (colc - 48)] = v + b3[colc - 48];\
                }                                                          \
            }                                                              \
        }                                                                  \
    }
    EPI3(0, acc0) EPI3(1, acc1) EPI3(2, acc2) EPI3(3, acc3) EPI3(4, acc4) EPI3(5, acc5)
#undef EPI3
}

// ---------------- agg(40 bf16) + self add + fused log_softmax: 8-lane group/node ----------------
// lanes 0..4 each own 8 dims (uint4 = 16B); shuffle reduce width 8.
__global__ __launch_bounds__(256) void agg40lsm_kernel(const unsigned short* __restrict__ Z,
                                                       const int* __restrict__ rs,
                                                       const int* __restrict__ col,
                                                       float* __restrict__ out, int n) {
    int t = threadIdx.x;
    int node = blockIdx.x * 32 + (t >> 3);
    if (node >= n) return;
    int lane = t & 7;
    bool act = lane < 5;
    int s = rs[node], d = rs[node + 1] - s;
    const unsigned short* lp = Z + lane * 8;
    float a0 = 0.f, a1 = 0.f, a2 = 0.f, a3 = 0.f, a4 = 0.f, a5 = 0.f, a6 = 0.f, a7 = 0.f;
    int j = 0;
    for (; j + 3 < d; j += 4) {
        int c0 = col[s + j], c1 = col[s + j + 1];
        int c2 = col[s + j + 2], c3 = col[s + j + 3];
        if (act) {
            uint4 q0 = *(const uint4*)(lp + (size_t)c0 * 40);
            uint4 q1 = *(const uint4*)(lp + (size_t)c1 * 40);
            uint4 q2 = *(const uint4*)(lp + (size_t)c2 * 40);
            uint4 q3 = *(const uint4*)(lp + (size_t)c3 * 40);
            a0 += (blo(q0.x) + blo(q1.x)) + (blo(q2.x) + blo(q3.x));
            a1 += (bhi(q0.x) + bhi(q1.x)) + (bhi(q2.x) + bhi(q3.x));
            a2 += (blo(q0.y) + blo(q1.y)) + (blo(q2.y) + blo(q3.y));
            a3 += (bhi(q0.y) + bhi(q1.y)) + (bhi(q2.y) + bhi(q3.y));
            a4 += (blo(q0.z) + blo(q1.z)) + (blo(q2.z) + blo(q3.z));
            a5 += (bhi(q0.z) + bhi(q1.z)) + (bhi(q2.z) + bhi(q3.z));
            a6 += (blo(q0.w) + blo(q1.w)) + (blo(q2.w) + blo(q3.w));
            a7 += (bhi(q0.w) + bhi(q1.w)) + (bhi(q2.w) + bhi(q3.w));
        }
    }
    for (; j < d; ++j) {
        int c0 = col[s + j];
        if (act) {
            uint4 q0 = *(const uint4*)(lp + (size_t)c0 * 40);
            a0 += blo(q0.x); a1 += bhi(q0.x); a2 += blo(q0.y); a3 += bhi(q0.y);
            a4 += blo(q0.z); a5 += bhi(q0.z); a6 += blo(q0.w); a7 += bhi(q0.w);
        }
    }
    float w = 1.f / (float)(d > 0 ? d : 1);
    if (act) {
        float* op = out + (size_t)node * 40 + lane * 8;
        float4 r0 = *(const float4*)op;
        float4 r1 = *(const float4*)(op + 4);
        a0 = a0 * w + r0.x; a1 = a1 * w + r0.y; a2 = a2 * w + r0.z; a3 = a3 * w + r0.w;
        a4 = a4 * w + r1.x; a5 = a5 * w + r1.y; a6 = a6 * w + r1.z; a7 = a7 * w + r1.w;
    }
    float mx = act ? fmaxf(fmaxf(fmaxf(a0, a1), fmaxf(a2, a3)),
                           fmaxf(fmaxf(a4, a5), fmaxf(a6, a7))) : -3.4e38f;
#pragma unroll
    for (int off = 1; off < 8; off <<= 1) mx = fmaxf(mx, __shfl_xor(mx, off, 8));
    float ssum = act ? (expf(a0 - mx) + expf(a1 - mx) + expf(a2 - mx) + expf(a3 - mx) +
                        expf(a4 - mx) + expf(a5 - mx) + expf(a6 - mx) + expf(a7 - mx)) : 0.f;
#pragma unroll
    for (int off = 1; off < 8; off <<= 1) ssum += __shfl_xor(ssum, off, 8);
    float lg = mx + logf(ssum);
    if (act) {
        float* op = out + (size_t)node * 40 + lane * 8;
        float4 o0, o1;
        o0.x = a0 - lg; o0.y = a1 - lg; o0.z = a2 - lg; o0.w = a3 - lg;
        o1.x = a4 - lg; o1.y = a5 - lg; o1.z = a6 - lg; o1.w = a7 - lg;
        *(float4*)op = o0;
        *(float4*)(op + 4) = o1;
    }
}

// ---------------- launch ----------------
extern "C" void kernel_launch(void* const* d_in, const int* in_sizes, int n_in,
                              void* d_out, int out_size, void* d_ws, size_t ws_size,
                              hipStream_t stream) {
    const float* x   = (const float*)d_in[0];
    const int*   ei  = (const int*)d_in[1];
    const float* Wl1 = (const float*)d_in[2];
    const float* Wr1 = (const float*)d_in[3];
    const float* b1  = (const float*)d_in[4];
    const float* Wl2 = (const float*)d_in[5];
    const float* Wr2 = (const float*)d_in[6];
    const float* b2  = (const float*)d_in[7];
    const float* Wl3 = (const float*)d_in[8];
    const float* Wr3 = (const float*)d_in[9];
    const float* b3  = (const float*)d_in[10];
    float* out = (float*)d_out;

    const int N = in_sizes[0] / 64;
    const int E = in_sizes[1] / 2;
    const int NB = (N + BK_NODES - 1) / BK_NODES;
    const int* srcA = ei;
    const int* dstA = ei + E;

    char* ws = (char*)d_ws;
    size_t off = 0;
    auto alloc = [&](size_t bytes) {
        off = (off + 255) & ~(size_t)255;
        char* p = ws + off;
        off += bytes;
        return p;
    };
    int* bcount    = (int*)alloc((size_t)(NB_MAX + 1) * 4);
    int* bbase     = (int*)alloc((size_t)(NB_MAX + 1) * 4);
    int* cursor    = (int*)alloc((size_t)NB_MAX * 4);
    int* binned    = (int*)alloc((size_t)E * 4);
    int* col       = (int*)alloc((size_t)E * 4);
    int* row_start = (int*)alloc((size_t)(N + 1) * 4);
    unsigned short* Xb  = (unsigned short*)alloc((size_t)N * 64 * 2);
    unsigned short* AGG = (unsigned short*)alloc((size_t)N * 64 * 2);
    unsigned short* Hb  = (unsigned short*)alloc((size_t)N * 64 * 2);
    unsigned short* Zb  = (unsigned short*)alloc((size_t)N * 40 * 2);
    unsigned short* Wb1 = (unsigned short*)alloc(8192 * 2);
    unsigned short* Wb2 = (unsigned short*)alloc(8192 * 2);
    unsigned short* Wb3 = (unsigned short*)alloc(6144 * 2);

    // build sorted CSR via dst-buckets (+ fused dtype conversions)
    hipMemsetAsync(bcount, 0, (size_t)(NB + 1) * 4, stream);
    prep_kernel<<<1368, 256, 0, stream>>>(dstA, bcount, E, NB, x, Xb, N * 64 / 8,
                                          Wl1, Wr1, Wl2, Wr2, Wl3, Wr3, Wb1, Wb2, Wb3);
    bscan_kernel<<<1, 1024, 0, stream>>>(bcount, bbase, cursor, NB, E);
    bin_kernel<<<512, 256, 0, stream>>>(srcA, dstA, cursor, binned, E, NB);
    bsort_kernel<<<NB, 256, 0, stream>>>(binned, bbase, col, row_start, N);

    int gridA = (N + 31) / 32;
    int gridM = (N + 63) / 64;

    // layer 1
    agg64_kernel<<<gridA, 256, 0, stream>>>(Xb, row_start, col, AGG, N);
    linmfma12_kernel<<<gridM, 256, 0, stream>>>(AGG, Xb, Wb1, b1, Hb, N);

    // layer 2 (lin in-place on Hb: each block stages its own rows before writing)
    agg64_kernel<<<gridA, 256, 0, stream>>>(Hb, row_start, col, AGG, N);
    linmfma12_kernel<<<gridM, 256, 0, stream>>>(AGG, Hb, Wb2, b2, Hb, N);

    // layer 3: pre-transform (agg is linear), then agg(40) + self + log_softmax
    linmfma3_kernel<<<gridM, 256, 0, stream>>>(Hb, Wb3, b3, Zb, out, N);
    agg40lsm_kernel<<<gridA, 256, 0, stream>>>(Zb, row_start, col, out, N);
}